// Round 7
// baseline (262.552 us; speedup 1.0000x reference)
//
#include <hip/hip_runtime.h>

#define D_EMB 768
#define NH 12
#define DK 64
#define NB 2
#define SS 4096
#define E3 (3*D_EMB)   // 2304
#define MM (NB*SS)     // 8192

typedef unsigned short u16;
typedef __attribute__((ext_vector_type(8))) __bf16 bf16x8;
typedef __attribute__((ext_vector_type(4))) float f32x4;
typedef __attribute__((ext_vector_type(4))) unsigned int u32x4;

static __device__ __forceinline__ u16 f2bf(float f) {
  unsigned u = __builtin_bit_cast(unsigned, f);
  u += 0x7fffu + ((u >> 16) & 1u);          // round-to-nearest-even
  return (u16)(u >> 16);
}
static __device__ __forceinline__ f32x4 mfma16(bf16x8 a, bf16x8 b, f32x4 c) {
  return __builtin_amdgcn_mfma_f32_16x16x32_bf16(a, b, c, 0, 0, 0);
}
static __device__ __forceinline__ float exp2_fast(float x) {
#if __has_builtin(__builtin_amdgcn_exp2f)
  return __builtin_amdgcn_exp2f(x);
#else
  return __builtin_exp2f(x);
#endif
}
static __device__ __forceinline__ float rcp_fast(float x) {
#if __has_builtin(__builtin_amdgcn_rcpf)
  return __builtin_amdgcn_rcpf(x);
#else
  return 1.f / x;
#endif
}
static __device__ __forceinline__ void gload_lds16(const u16* g, u16* l) {
  __builtin_amdgcn_global_load_lds((const __attribute__((address_space(1))) void*)g,
                                   (__attribute__((address_space(3))) void*)l, 16, 0, 0);
}

// ---------------- cast fp32 -> bf16, elementwise ----------------
__global__ __launch_bounds__(256) void cast_kernel(const float* __restrict__ in,
                                                   u16* __restrict__ out, int n) {
  int i = (blockIdx.x * 256 + threadIdx.x) * 4;
  if (i + 3 < n) {
    float4 v = *(const float4*)(in + i);
    out[i + 0] = f2bf(v.x);
    out[i + 1] = f2bf(v.y);
    out[i + 2] = f2bf(v.z);
    out[i + 3] = f2bf(v.w);
  }
}

// -------- transpose + cast all four weights (z selects): WT[n][k] = W[k][n] * scale --------
__global__ __launch_bounds__(256) void transpose_cast_all(const float* __restrict__ Wq,
                                                          const float* __restrict__ Wk,
                                                          const float* __restrict__ Wv,
                                                          const float* __restrict__ Wo,
                                                          u16* __restrict__ WTqkv,
                                                          u16* __restrict__ WoT, float qscale) {
  __shared__ float tile[32][33];
  int z = blockIdx.z;
  const float* W = (z == 0) ? Wq : (z == 1) ? Wk : (z == 2) ? Wv : Wo;
  u16* WT = (z < 3) ? WTqkv + (size_t)z * D_EMB * D_EMB : WoT;
  float scale = (z == 0) ? qscale : 1.0f;
  int kb = blockIdx.y * 32, nb = blockIdx.x * 32;
  int tx = threadIdx.x, ty = threadIdx.y;
#pragma unroll
  for (int i = 0; i < 4; i++)
    tile[ty + i * 8][tx] = W[(size_t)(kb + ty + i * 8) * D_EMB + nb + tx];
  __syncthreads();
#pragma unroll
  for (int i = 0; i < 4; i++)
    WT[(size_t)(nb + ty + i * 8) * D_EMB + kb + tx] = f2bf(tile[tx][ty + i * 8] * scale);
}

// -------- transpose V (bf16), pi-permuted columns within each 64-block --------
__global__ __launch_bounds__(256) void transpose_v(const u16* __restrict__ QKV,
                                                   u16* __restrict__ VT) {
  __shared__ u16 tile[32][33];
  int bh = blockIdx.z;
  int b = bh / NH, h = bh % NH;
  int sb = blockIdx.x * 32, db = blockIdx.y * 32;
  int tx = threadIdx.x, ty = threadIdx.y;
  const u16* src = QKV + (size_t)(b * SS) * E3 + 2 * D_EMB + h * DK;
  u16* dst = VT + (size_t)bh * DK * SS;
#pragma unroll
  for (int i = 0; i < 4; i++)
    tile[ty + i * 8][tx] = src[(size_t)(sb + ty + i * 8) * E3 + db + tx];
  __syncthreads();
  int s = sb + tx;
  int k6 = s & 63;
  int p = (s & ~63) | (k6 & 0x23) | ((k6 & 0x0C) << 1) | ((k6 & 0x10) >> 2);
#pragma unroll
  for (int i = 0; i < 4; i++)
    dst[(size_t)(db + ty + i * 8) * SS + p] = tile[tx][ty + i * 8];
}

// ---------------- bf16 GEMM, B given transposed ----------------
// v3 (verified, round 6): BK=64 + XOR swizzle + flash's single-barrier
// double-buffered schedule. LDS 64 KB.
template <int OUTF32>
__global__ __launch_bounds__(256) void gemm_bt(const u16* __restrict__ A,
                                               const u16* __restrict__ Bt,
                                               void* __restrict__ Cout,
                                               int M, int N, int K, float scale) {
  __shared__ __align__(16) u16 As[2 * 128 * 64];
  __shared__ __align__(16) u16 Bs[2 * 128 * 64];
  int tid = threadIdx.x;
  int wave = tid >> 6, lane = tid & 63;
  int g = lane >> 4, nIdx = lane & 15;
  int m0 = blockIdx.y * 128, n0 = blockIdx.x * 128;
  int wm = (wave >> 1) * 64, wn = (wave & 1) * 64;

  f32x4 acc[4][4] = {};

  int rL = lane >> 3, cL = lane & 7;
  int xr8 = (cL ^ rL) * 8;                    // source-side XOR swizzle
  int xrn = nIdx & 7;
  int nk = K >> 6;

  // prologue: stage K-tile 0 into buf 0
#pragma unroll
  for (int i = 0; i < 4; i++) {
    int r = (wave * 4 + i) * 8 + rL;          // tile row 0..127
    gload_lds16(A  + (size_t)(m0 + r) * K + xr8,
                As + (wave * 4 + i) * 512 + lane * 8);
    gload_lds16(Bt + (size_t)(n0 + r) * K + xr8,
                Bs + (wave * 4 + i) * 512 + lane * 8);
  }

  for (int kt = 0; kt < nk; kt++) {
    __syncthreads();                          // buf[kt&1] glls complete & visible

    int cb = (kt & 1) * 8192;

    if (kt + 1 < nk) {                        // async prefetch into buf[(kt+1)&1]
      int nb = ((kt + 1) & 1) * 8192;
      int k0n = (kt + 1) << 6;
#pragma unroll
      for (int i = 0; i < 4; i++) {
        int r = (wave * 4 + i) * 8 + rL;
        gload_lds16(A  + (size_t)(m0 + r) * K + k0n + xr8,
                    As + nb + (wave * 4 + i) * 512 + lane * 8);
        gload_lds16(Bt + (size_t)(n0 + r) * K + k0n + xr8,
                    Bs + nb + (wave * 4 + i) * 512 + lane * 8);
      }
    }

#pragma unroll
    for (int ks = 0; ks < 2; ks++) {
      bf16x8 af[4], bfr[4];
#pragma unroll
      for (int i = 0; i < 4; i++)
        af[i] = *(const bf16x8*)(As + cb + (wm + i * 16 + nIdx) * 64 + ((ks * 4 + g) ^ xrn) * 8);
#pragma unroll
      for (int j = 0; j < 4; j++)
        bfr[j] = *(const bf16x8*)(Bs + cb + (wn + j * 16 + nIdx) * 64 + ((ks * 4 + g) ^ xrn) * 8);
#pragma unroll
      for (int i = 0; i < 4; i++)
#pragma unroll
        for (int j = 0; j < 4; j++)
          acc[i][j] = mfma16(af[i], bfr[j], acc[i][j]);
    }
  }

#pragma unroll
  for (int i = 0; i < 4; i++)
#pragma unroll
    for (int j = 0; j < 4; j++)
#pragma unroll
      for (int r = 0; r < 4; r++) {
        int rr = m0 + wm + i * 16 + g * 4 + r;
        int cc = n0 + wn + j * 16 + nIdx;
        float v = acc[i][j][r] * scale;
        if (OUTF32)
          ((float*)Cout)[(size_t)rr * N + cc] = v;
        else
          ((u16*)Cout)[(size_t)rr * N + cc] = f2bf(v);
      }
}

// ---------------- flash attention v14 ----------------
// v9's verified 1-barrier double-buffered schedule and per-(q,kv) compute,
// restructured from 2 independent kv-streams to ONE shared 64-kv tile:
//  - each wave owns 32 q rows (was 64) and iterates all 64 kv tiles
//  - waves 0,1 stage K, waves 2,3 stage V (4 glls/thread/tile), same XOR
//    swizzle algebra, same wave-uniform + lane*16B gll dest form
//  - LDS: K[2][64][64] + V[2][64][64] = 32 KB (was 64) -> grid 768 gives
//    exactly 3 blocks/CU resident = 3 waves/SIMD (was 2), no tail
//  - merge phase GONE (each wave sees all kv): no dump, direct O write
// Same MFMA products; kv accumulation order changes (sequential 64 tiles
// vs two merged 32-tile halves) -> absmax may drift within tolerance.
__global__ __launch_bounds__(256, 2) void flash(const u16* __restrict__ QKV,
                                                const u16* __restrict__ VT,
                                                u16* __restrict__ O) {
  // K: [buf][64 kv][64 dk] at [0,8192); V: [buf][64 dk][64 kv] at [8192,16384)
  __shared__ __align__(16) u16 smem[16384];

  int b = blockIdx.z, h = blockIdx.y;
  int q0 = blockIdx.x * 128;
  int tid = threadIdx.x, w = tid >> 6, l = tid & 63;
  int g = l >> 4, n = l & 15;

  const u16* VTb = VT + (size_t)(b * NH + h) * DK * SS;

  // --- Q fragments: 32 rows for this wave ---
  const u16* Qbase = QKV + (size_t)(b * SS + q0 + w * 32) * E3 + h * DK;
  bf16x8 qf[2][2];
#pragma unroll
  for (int qg = 0; qg < 2; qg++)
#pragma unroll
    for (int hf = 0; hf < 2; hf++)
      qf[qg][hf] = *(const bf16x8*)(Qbase + (size_t)(qg * 16 + n) * E3 + hf * 32 + g * 8);

  f32x4 o_acc[2][4] = {};
  float lsum[2] = {0.f, 0.f};
  u32x4 onev = {0x3F803F80u, 0x3F803F80u, 0x3F803F80u, 0x3F803F80u};
  bf16x8 aone = __builtin_bit_cast(bf16x8, onev);

  // --- staging: waves 0,1 stage K; waves 2,3 stage V; 4 glls/thread/tile ---
  int t = tid & 127;
  int rT = t >> 3, cT = t & 7;                // row-in-group 0..15, chunk 0..7
  int xr8 = (cT ^ (rT & 7)) * 8;              // source-side XOR swizzle
  const u16* g0;
  size_t rstep, tstep;
  u16* sd0;                                   // per-lane LDS dest: uniform + t*16B
  if (w < 2) {
    g0 = QKV + ((size_t)(b * SS) + rT) * E3 + D_EMB + h * DK + xr8;
    rstep = (size_t)16 * E3;
    tstep = (size_t)64 * E3;
    sd0 = smem + t * 8;
  } else {
    g0 = VTb + (size_t)rT * SS + xr8;
    rstep = (size_t)16 * SS;
    tstep = 64;
    sd0 = smem + 8192 + t * 8;
  }

  // prologue: stage tile 0 into buffer 0
#pragma unroll
  for (int i = 0; i < 4; i++)
    gload_lds16(g0 + i * rstep, sd0 + i * 1024);

  int xrn = (n & 7);
  for (int kt = 0; kt < 64; kt++) {
    __syncthreads();                          // buf[kt&1] glls complete & visible

    const u16* pK = smem + (kt & 1) * 4096;
    const u16* pV = smem + 8192 + (kt & 1) * 4096;

    if (kt < 63) {                            // async prefetch into buf[(kt+1)&1]
      const u16* gn = g0 + (size_t)(kt + 1) * tstep;
      u16* sd = sd0 + ((kt + 1) & 1) * 4096;
#pragma unroll
      for (int i = 0; i < 4; i++)
        gload_lds16(gn + i * rstep, sd + i * 1024);
    }

#pragma unroll
    for (int s = 0; s < 2; s++) {             // 32-kv sub-round
      bf16x8 kf[2][2];
#pragma unroll
      for (int jj = 0; jj < 2; jj++)
#pragma unroll
        for (int hf = 0; hf < 2; hf++)
          kf[jj][hf] = *(const bf16x8*)(pK + ((2 * s + jj) * 16 + n) * 64 +
                                        ((hf * 4 + g) ^ xrn) * 8);

      f32x4 C[2][2];
#pragma unroll
      for (int q2 = 0; q2 < 2; q2++)
#pragma unroll
        for (int jj = 0; jj < 2; jj++) {
          f32x4 tacc = {};
          tacc = mfma16(kf[jj][0], qf[q2][0], tacc);
          tacc = mfma16(kf[jj][1], qf[q2][1], tacc);
          C[q2][jj] = tacc;
        }
      u32x4 Bw[2];
#pragma unroll
      for (int q2 = 0; q2 < 2; q2++)
#pragma unroll
        for (int jj = 0; jj < 2; jj++) {
          float p0 = exp2_fast(C[q2][jj][0]);
          float p1 = exp2_fast(C[q2][jj][1]);
          float p2 = exp2_fast(C[q2][jj][2]);
          float p3 = exp2_fast(C[q2][jj][3]);
          Bw[q2][jj * 2] = __builtin_amdgcn_perm(__builtin_bit_cast(unsigned, p1),
                                                 __builtin_bit_cast(unsigned, p0), 0x07060302u);
          Bw[q2][jj * 2 + 1] = __builtin_amdgcn_perm(__builtin_bit_cast(unsigned, p3),
                                                     __builtin_bit_cast(unsigned, p2), 0x07060302u);
        }
#pragma unroll
      for (int q2 = 0; q2 < 2; q2++) {
        f32x4 z = {};
        z = mfma16(aone, __builtin_bit_cast(bf16x8, Bw[q2]), z);
        lsum[q2] += z[0];
      }
#pragma unroll
      for (int dt = 0; dt < 4; dt++) {
        bf16x8 vf = *(const bf16x8*)(pV + (dt * 16 + n) * 64 +
                                     ((s * 4 + g) ^ xrn) * 8);
#pragma unroll
        for (int q2 = 0; q2 < 2; q2++)
          o_acc[q2][dt] = mfma16(vf, __builtin_bit_cast(bf16x8, Bw[q2]),
                                 o_acc[q2][dt]);
      }
    }
  }

  // --- epilogue: each wave owns its 32 q rows completely; direct write ---
#pragma unroll
  for (int qg = 0; qg < 2; qg++) {
    float rl = rcp_fast(lsum[qg]);
    u16* Obp = O + (size_t)(b * SS + q0 + w * 32 + qg * 16 + n) * D_EMB + h * DK;
#pragma unroll
    for (int dt = 0; dt < 4; dt++) {
      uint2 pk;
      pk.x = (unsigned)f2bf(o_acc[qg][dt][0] * rl) |
             ((unsigned)f2bf(o_acc[qg][dt][1] * rl) << 16);
      pk.y = (unsigned)f2bf(o_acc[qg][dt][2] * rl) |
             ((unsigned)f2bf(o_acc[qg][dt][3] * rl) << 16);
      *(uint2*)(Obp + dt * 16 + g * 4) = pk;
    }
  }
}

extern "C" void kernel_launch(void* const* d_in, const int* in_sizes, int n_in,
                              void* d_out, int out_size, void* d_ws, size_t ws_size,
                              hipStream_t stream) {
  const float* X  = (const float*)d_in[0];
  const float* Wq = (const float*)d_in[1];
  const float* Wk = (const float*)d_in[2];
  const float* Wv = (const float*)d_in[3];
  const float* Wo = (const float*)d_in[4];
  float* out = (float*)d_out;

  u16* Xb    = (u16*)d_ws;                         // MM*D_EMB
  u16* WTqkv = Xb + (size_t)MM * D_EMB;            // E3*D_EMB
  u16* WoT   = WTqkv + (size_t)E3 * D_EMB;         // D_EMB*D_EMB
  u16* QKV   = WoT + (size_t)D_EMB * D_EMB;        // MM*E3
  u16* VT    = QKV + (size_t)MM * E3;              // NB*NH*DK*SS
  u16* Ob    = VT + (size_t)NB * NH * DK * SS;     // MM*D_EMB

  dim3 tb(32, 8);
  cast_kernel<<<(MM * D_EMB) / 1024, 256, 0, stream>>>(X, Xb, MM * D_EMB);
  transpose_cast_all<<<dim3(24, 24, 4), tb, 0, stream>>>(Wq, Wk, Wv, Wo, WTqkv, WoT,
                                                         0.125f * 1.4426950408889634f);
  gemm_bt<0><<<dim3(E3 / 128, MM / 128), 256, 0, stream>>>(Xb, WTqkv, (void*)QKV,
                                                           MM, E3, D_EMB, 1.0f);
  transpose_v<<<dim3(SS / 32, 2, NB * NH), tb, 0, stream>>>(QKV, VT);
  flash<<<dim3(SS / 128, NH, NB), 256, 0, stream>>>(QKV, VT, Ob);
  gemm_bt<1><<<dim3(D_EMB / 128, MM / 128), 256, 0, stream>>>(Ob, WoT, (void*)out,
                                                              MM, D_EMB, D_EMB, 1.0f);
}

// Round 9
// 260.507 us; speedup vs baseline: 1.0079x; 1.0079x over previous
//
#include <hip/hip_runtime.h>

#define D_EMB 768
#define NH 12
#define DK 64
#define NB 2
#define SS 4096
#define E3 (3*D_EMB)   // 2304
#define MM (NB*SS)     // 8192

typedef unsigned short u16;
typedef __attribute__((ext_vector_type(8))) __bf16 bf16x8;
typedef __attribute__((ext_vector_type(4))) float f32x4;
typedef __attribute__((ext_vector_type(4))) unsigned int u32x4;

static __device__ __forceinline__ u16 f2bf(float f) {
  unsigned u = __builtin_bit_cast(unsigned, f);
  u += 0x7fffu + ((u >> 16) & 1u);          // round-to-nearest-even
  return (u16)(u >> 16);
}
static __device__ __forceinline__ f32x4 mfma16(bf16x8 a, bf16x8 b, f32x4 c) {
  return __builtin_amdgcn_mfma_f32_16x16x32_bf16(a, b, c, 0, 0, 0);
}
static __device__ __forceinline__ float exp2_fast(float x) {
#if __has_builtin(__builtin_amdgcn_exp2f)
  return __builtin_amdgcn_exp2f(x);
#else
  return __builtin_exp2f(x);
#endif
}
static __device__ __forceinline__ float rcp_fast(float x) {
#if __has_builtin(__builtin_amdgcn_rcpf)
  return __builtin_amdgcn_rcpf(x);
#else
  return 1.f / x;
#endif
}
static __device__ __forceinline__ void gload_lds16(const u16* g, u16* l) {
  __builtin_amdgcn_global_load_lds((const __attribute__((address_space(1))) void*)g,
                                   (__attribute__((address_space(3))) void*)l, 16, 0, 0);
}

// ---------------- cast fp32 -> bf16, elementwise ----------------
__global__ __launch_bounds__(256) void cast_kernel(const float* __restrict__ in,
                                                   u16* __restrict__ out, int n) {
  int i = (blockIdx.x * 256 + threadIdx.x) * 4;
  if (i + 3 < n) {
    float4 v = *(const float4*)(in + i);
    out[i + 0] = f2bf(v.x);
    out[i + 1] = f2bf(v.y);
    out[i + 2] = f2bf(v.z);
    out[i + 3] = f2bf(v.w);
  }
}

// -------- transpose + cast all four weights (z selects): WT[n][k] = W[k][n] * scale --------
__global__ __launch_bounds__(256) void transpose_cast_all(const float* __restrict__ Wq,
                                                          const float* __restrict__ Wk,
                                                          const float* __restrict__ Wv,
                                                          const float* __restrict__ Wo,
                                                          u16* __restrict__ WTqkv,
                                                          u16* __restrict__ WoT, float qscale) {
  __shared__ float tile[32][33];
  int z = blockIdx.z;
  const float* W = (z == 0) ? Wq : (z == 1) ? Wk : (z == 2) ? Wv : Wo;
  u16* WT = (z < 3) ? WTqkv + (size_t)z * D_EMB * D_EMB : WoT;
  float scale = (z == 0) ? qscale : 1.0f;
  int kb = blockIdx.y * 32, nb = blockIdx.x * 32;
  int tx = threadIdx.x, ty = threadIdx.y;
#pragma unroll
  for (int i = 0; i < 4; i++)
    tile[ty + i * 8][tx] = W[(size_t)(kb + ty + i * 8) * D_EMB + nb + tx];
  __syncthreads();
#pragma unroll
  for (int i = 0; i < 4; i++)
    WT[(size_t)(nb + ty + i * 8) * D_EMB + kb + tx] = f2bf(tile[tx][ty + i * 8] * scale);
}

// -------- transpose V (bf16), pi-permuted columns within each 64-block --------
__global__ __launch_bounds__(256) void transpose_v(const u16* __restrict__ QKV,
                                                   u16* __restrict__ VT) {
  __shared__ u16 tile[32][33];
  int bh = blockIdx.z;
  int b = bh / NH, h = bh % NH;
  int sb = blockIdx.x * 32, db = blockIdx.y * 32;
  int tx = threadIdx.x, ty = threadIdx.y;
  const u16* src = QKV + (size_t)(b * SS) * E3 + 2 * D_EMB + h * DK;
  u16* dst = VT + (size_t)bh * DK * SS;
#pragma unroll
  for (int i = 0; i < 4; i++)
    tile[ty + i * 8][tx] = src[(size_t)(sb + ty + i * 8) * E3 + db + tx];
  __syncthreads();
  int s = sb + tx;
  int k6 = s & 63;
  int p = (s & ~63) | (k6 & 0x23) | ((k6 & 0x0C) << 1) | ((k6 & 0x10) >> 2);
#pragma unroll
  for (int i = 0; i < 4; i++)
    dst[(size_t)(db + ty + i * 8) * SS + p] = tile[tx][ty + i * 8];
}

// ---------------- bf16 GEMM, B given transposed ----------------
// v3 (verified, round 6): BK=64 + XOR swizzle + flash's single-barrier
// double-buffered schedule. LDS 64 KB.
template <int OUTF32>
__global__ __launch_bounds__(256) void gemm_bt(const u16* __restrict__ A,
                                               const u16* __restrict__ Bt,
                                               void* __restrict__ Cout,
                                               int M, int N, int K, float scale) {
  __shared__ __align__(16) u16 As[2 * 128 * 64];
  __shared__ __align__(16) u16 Bs[2 * 128 * 64];
  int tid = threadIdx.x;
  int wave = tid >> 6, lane = tid & 63;
  int g = lane >> 4, nIdx = lane & 15;
  int m0 = blockIdx.y * 128, n0 = blockIdx.x * 128;
  int wm = (wave >> 1) * 64, wn = (wave & 1) * 64;

  f32x4 acc[4][4] = {};

  int rL = lane >> 3, cL = lane & 7;
  int xr8 = (cL ^ rL) * 8;                    // source-side XOR swizzle
  int xrn = nIdx & 7;
  int nk = K >> 6;

  // prologue: stage K-tile 0 into buf 0
#pragma unroll
  for (int i = 0; i < 4; i++) {
    int r = (wave * 4 + i) * 8 + rL;          // tile row 0..127
    gload_lds16(A  + (size_t)(m0 + r) * K + xr8,
                As + (wave * 4 + i) * 512 + lane * 8);
    gload_lds16(Bt + (size_t)(n0 + r) * K + xr8,
                Bs + (wave * 4 + i) * 512 + lane * 8);
  }

  for (int kt = 0; kt < nk; kt++) {
    __syncthreads();                          // buf[kt&1] glls complete & visible

    int cb = (kt & 1) * 8192;

    if (kt + 1 < nk) {                        // async prefetch into buf[(kt+1)&1]
      int nb = ((kt + 1) & 1) * 8192;
      int k0n = (kt + 1) << 6;
#pragma unroll
      for (int i = 0; i < 4; i++) {
        int r = (wave * 4 + i) * 8 + rL;
        gload_lds16(A  + (size_t)(m0 + r) * K + k0n + xr8,
                    As + nb + (wave * 4 + i) * 512 + lane * 8);
        gload_lds16(Bt + (size_t)(n0 + r) * K + k0n + xr8,
                    Bs + nb + (wave * 4 + i) * 512 + lane * 8);
      }
    }

#pragma unroll
    for (int ks = 0; ks < 2; ks++) {
      bf16x8 af[4], bfr[4];
#pragma unroll
      for (int i = 0; i < 4; i++)
        af[i] = *(const bf16x8*)(As + cb + (wm + i * 16 + nIdx) * 64 + ((ks * 4 + g) ^ xrn) * 8);
#pragma unroll
      for (int j = 0; j < 4; j++)
        bfr[j] = *(const bf16x8*)(Bs + cb + (wn + j * 16 + nIdx) * 64 + ((ks * 4 + g) ^ xrn) * 8);
#pragma unroll
      for (int i = 0; i < 4; i++)
#pragma unroll
        for (int j = 0; j < 4; j++)
          acc[i][j] = mfma16(af[i], bfr[j], acc[i][j]);
    }
  }

#pragma unroll
  for (int i = 0; i < 4; i++)
#pragma unroll
    for (int j = 0; j < 4; j++)
#pragma unroll
      for (int r = 0; r < 4; r++) {
        int rr = m0 + wm + i * 16 + g * 4 + r;
        int cc = n0 + wn + j * 16 + nIdx;
        float v = acc[i][j][r] * scale;
        if (OUTF32)
          ((float*)Cout)[(size_t)rr * N + cc] = v;
        else
          ((u16*)Cout)[(size_t)rr * N + cc] = f2bf(v);
      }
}

// ---------------- flash attention v16 ----------------
// v14 (shared 64-kv tile, 1-barrier dbuf, 3 blocks/CU, verified) with ONLY
// the exact VALU savings kept from v15:
//  - persistent fzero quad as C for QK chain heads AND the lsum MFMA
//    (C=0 exactly in both old and new forms -> bit-identical to v14)
//  - lsum accumulation stays on the VALU (lsum += z[0]): round-8 lesson —
//    carrying a long-running sum in the MFMA C operand makes the HW round
//    each of the 32 small products against the large base (32 big-magnitude
//    roundings per s-round instead of 1) -> 6.5x error growth. Reverted.
__global__ __launch_bounds__(256, 2) void flash(const u16* __restrict__ QKV,
                                                const u16* __restrict__ VT,
                                                u16* __restrict__ O) {
  // K: [buf][64 kv][64 dk] at [0,8192); V: [buf][64 dk][64 kv] at [8192,16384)
  __shared__ __align__(16) u16 smem[16384];

  int b = blockIdx.z, h = blockIdx.y;
  int q0 = blockIdx.x * 128;
  int tid = threadIdx.x, w = tid >> 6, l = tid & 63;
  int g = l >> 4, n = l & 15;

  const u16* VTb = VT + (size_t)(b * NH + h) * DK * SS;

  // --- Q fragments: 32 rows for this wave ---
  const u16* Qbase = QKV + (size_t)(b * SS + q0 + w * 32) * E3 + h * DK;
  bf16x8 qf[2][2];
#pragma unroll
  for (int qg = 0; qg < 2; qg++)
#pragma unroll
    for (int hf = 0; hf < 2; hf++)
      qf[qg][hf] = *(const bf16x8*)(Qbase + (size_t)(qg * 16 + n) * E3 + hf * 32 + g * 8);

  f32x4 o_acc[2][4] = {};
  float lsum[2] = {0.f, 0.f};
  const f32x4 fzero = {0.f, 0.f, 0.f, 0.f};   // shared C for chain heads
  u32x4 onev = {0x3F803F80u, 0x3F803F80u, 0x3F803F80u, 0x3F803F80u};
  bf16x8 aone = __builtin_bit_cast(bf16x8, onev);

  // --- staging: waves 0,1 stage K; waves 2,3 stage V; 4 glls/thread/tile ---
  int t = tid & 127;
  int rT = t >> 3, cT = t & 7;                // row-in-group 0..15, chunk 0..7
  int xr8 = (cT ^ (rT & 7)) * 8;              // source-side XOR swizzle
  const u16* g0;
  size_t rstep, tstep;
  u16* sd0;                                   // per-lane LDS dest: uniform + t*16B
  if (w < 2) {
    g0 = QKV + ((size_t)(b * SS) + rT) * E3 + D_EMB + h * DK + xr8;
    rstep = (size_t)16 * E3;
    tstep = (size_t)64 * E3;
    sd0 = smem + t * 8;
  } else {
    g0 = VTb + (size_t)rT * SS + xr8;
    rstep = (size_t)16 * SS;
    tstep = 64;
    sd0 = smem + 8192 + t * 8;
  }

  // prologue: stage tile 0 into buffer 0
#pragma unroll
  for (int i = 0; i < 4; i++)
    gload_lds16(g0 + i * rstep, sd0 + i * 1024);

  int xrn = (n & 7);
  for (int kt = 0; kt < 64; kt++) {
    __syncthreads();                          // buf[kt&1] glls complete & visible

    const u16* pK = smem + (kt & 1) * 4096;
    const u16* pV = smem + 8192 + (kt & 1) * 4096;

    if (kt < 63) {                            // async prefetch into buf[(kt+1)&1]
      const u16* gn = g0 + (size_t)(kt + 1) * tstep;
      u16* sd = sd0 + ((kt + 1) & 1) * 4096;
#pragma unroll
      for (int i = 0; i < 4; i++)
        gload_lds16(gn + i * rstep, sd + i * 1024);
    }

#pragma unroll
    for (int s = 0; s < 2; s++) {             // 32-kv sub-round
      bf16x8 kf[2][2];
#pragma unroll
      for (int jj = 0; jj < 2; jj++)
#pragma unroll
        for (int hf = 0; hf < 2; hf++)
          kf[jj][hf] = *(const bf16x8*)(pK + ((2 * s + jj) * 16 + n) * 64 +
                                        ((hf * 4 + g) ^ xrn) * 8);

      f32x4 C[2][2];
#pragma unroll
      for (int q2 = 0; q2 < 2; q2++)
#pragma unroll
        for (int jj = 0; jj < 2; jj++) {
          f32x4 tacc = mfma16(kf[jj][0], qf[q2][0], fzero);   // D != C, no init
          tacc = mfma16(kf[jj][1], qf[q2][1], tacc);
          C[q2][jj] = tacc;
        }
      u32x4 Bw[2];
#pragma unroll
      for (int q2 = 0; q2 < 2; q2++)
#pragma unroll
        for (int jj = 0; jj < 2; jj++) {
          float p0 = exp2_fast(C[q2][jj][0]);
          float p1 = exp2_fast(C[q2][jj][1]);
          float p2 = exp2_fast(C[q2][jj][2]);
          float p3 = exp2_fast(C[q2][jj][3]);
          Bw[q2][jj * 2] = __builtin_amdgcn_perm(__builtin_bit_cast(unsigned, p1),
                                                 __builtin_bit_cast(unsigned, p0), 0x07060302u);
          Bw[q2][jj * 2 + 1] = __builtin_amdgcn_perm(__builtin_bit_cast(unsigned, p3),
                                                     __builtin_bit_cast(unsigned, p2), 0x07060302u);
        }
#pragma unroll
      for (int q2 = 0; q2 < 2; q2++) {
        f32x4 z = mfma16(aone, __builtin_bit_cast(bf16x8, Bw[q2]), fzero);
        lsum[q2] += z[0];
      }
#pragma unroll
      for (int dt = 0; dt < 4; dt++) {
        bf16x8 vf = *(const bf16x8*)(pV + (dt * 16 + n) * 64 +
                                     ((s * 4 + g) ^ xrn) * 8);
#pragma unroll
        for (int q2 = 0; q2 < 2; q2++)
          o_acc[q2][dt] = mfma16(vf, __builtin_bit_cast(bf16x8, Bw[q2]),
                                 o_acc[q2][dt]);
      }
    }
  }

  // --- epilogue: each wave owns its 32 q rows completely; direct write ---
#pragma unroll
  for (int qg = 0; qg < 2; qg++) {
    float rl = rcp_fast(lsum[qg]);
    u16* Obp = O + (size_t)(b * SS + q0 + w * 32 + qg * 16 + n) * D_EMB + h * DK;
#pragma unroll
    for (int dt = 0; dt < 4; dt++) {
      uint2 pk;
      pk.x = (unsigned)f2bf(o_acc[qg][dt][0] * rl) |
             ((unsigned)f2bf(o_acc[qg][dt][1] * rl) << 16);
      pk.y = (unsigned)f2bf(o_acc[qg][dt][2] * rl) |
             ((unsigned)f2bf(o_acc[qg][dt][3] * rl) << 16);
      *(uint2*)(Obp + dt * 16 + g * 4) = pk;
    }
  }
}

extern "C" void kernel_launch(void* const* d_in, const int* in_sizes, int n_in,
                              void* d_out, int out_size, void* d_ws, size_t ws_size,
                              hipStream_t stream) {
  const float* X  = (const float*)d_in[0];
  const float* Wq = (const float*)d_in[1];
  const float* Wk = (const float*)d_in[2];
  const float* Wv = (const float*)d_in[3];
  const float* Wo = (const float*)d_in[4];
  float* out = (float*)d_out;

  u16* Xb    = (u16*)d_ws;                         // MM*D_EMB
  u16* WTqkv = Xb + (size_t)MM * D_EMB;            // E3*D_EMB
  u16* WoT   = WTqkv + (size_t)E3 * D_EMB;         // D_EMB*D_EMB
  u16* QKV   = WoT + (size_t)D_EMB * D_EMB;        // MM*E3
  u16* VT    = QKV + (size_t)MM * E3;              // NB*NH*DK*SS
  u16* Ob    = VT + (size_t)NB * NH * DK * SS;     // MM*D_EMB

  dim3 tb(32, 8);
  cast_kernel<<<(MM * D_EMB) / 1024, 256, 0, stream>>>(X, Xb, MM * D_EMB);
  transpose_cast_all<<<dim3(24, 24, 4), tb, 0, stream>>>(Wq, Wk, Wv, Wo, WTqkv, WoT,
                                                         0.125f * 1.4426950408889634f);
  gemm_bt<0><<<dim3(E3 / 128, MM / 128), 256, 0, stream>>>(Xb, WTqkv, (void*)QKV,
                                                           MM, E3, D_EMB, 1.0f);
  transpose_v<<<dim3(SS / 32, 2, NB * NH), tb, 0, stream>>>(QKV, VT);
  flash<<<dim3(SS / 128, NH, NB), 256, 0, stream>>>(QKV, VT, Ob);
  gemm_bt<1><<<dim3(D_EMB / 128, MM / 128), 256, 0, stream>>>(Ob, WoT, (void*)out,
                                                              MM, D_EMB, D_EMB, 1.0f);
}